// Round 1
// baseline (858.055 us; speedup 1.0000x reference)
//
#include <hip/hip_runtime.h>
#include <hip/hip_bf16.h>
#include <math.h>

// Problem constants
#define B_ 32
#define T_ 4096
#define QD_ 1024
#define MD_ 512
#define AD_ 128
#define F_ 32
#define K_ 31
#define PAD_ 15

#define TT 64   // timesteps per score block
#define MC 32   // MD chunk

// ---------------- K1: processed query (no biases; biases folded in k_score) ----
__global__ __launch_bounds__(128) void k_pq(const float* __restrict__ query,
                                            const float* __restrict__ Wq,
                                            float* __restrict__ pq) {
    int b = blockIdx.x;       // 0..31
    int qc = blockIdx.y;      // 0..7  (chunk of 128 over QD)
    int a = threadIdx.x;      // 0..127
    const float* qrow = query + b * QD_ + qc * 128;
    const float* wq = Wq + (qc * 128) * AD_ + a;
    float acc = 0.f;
#pragma unroll 4
    for (int i = 0; i < 128; i++) acc += qrow[i] * wq[i * AD_];
    atomicAdd(&pq[b * AD_ + a], acc);
}

// ---------------- K2: fused conv + projections + tanh-score ----------------
__global__ __launch_bounds__(256) void k_score(
    const float* __restrict__ memory, const float* __restrict__ alignments,
    const unsigned char* __restrict__ mask,
    const float* __restrict__ Wm, const float* __restrict__ bm,
    const float* __restrict__ convw, const float* __restrict__ convb,
    const float* __restrict__ Wl, const float* __restrict__ bl,
    const float* __restrict__ vw, const float* __restrict__ vb,
    const float* __restrict__ pq, const float* __restrict__ bq,
    float* __restrict__ scores) {
    __shared__ float s_base[TT * AD_];        // 32 KB: pq + pl + biases
    __shared__ float s_convw[F_ * 2 * K_];    // 1984 floats
    __shared__ float s_align[(TT + K_ - 1) * 2];
    __shared__ float s_loc[TT * F_];          // 2048 floats
    __shared__ float s_mem[MC * 68];          // transposed [m][t], pad 68
    __shared__ float s_wm[MC * AD_];          // [m][a]

    const int tid = threadIdx.x;
    const int b = blockIdx.y;
    const int t0 = blockIdx.x * TT;

    // --- stage conv weights + alignment window ---
    for (int i = tid; i < F_ * 2 * K_; i += 256) s_convw[i] = convw[i];
    for (int i = tid; i < (TT + K_ - 1) * 2; i += 256) {
        int tg = t0 + (i >> 1) - PAD_;
        s_align[i] = (tg >= 0 && tg < T_) ? alignments[((long)b * T_ + tg) * 2 + (i & 1)] : 0.f;
    }
    __syncthreads();

    // --- location conv: loc[t][f] ---
    for (int i = tid; i < TT * F_; i += 256) {
        int f = i & (F_ - 1);
        int t = i >> 5;
        float acc = convb[f];
        const float* w0 = &s_convw[f * (2 * K_)];          // c=0
        const float* w1 = w0 + K_;                         // c=1
        const float* al = &s_align[t * 2];
#pragma unroll
        for (int k = 0; k < K_; k++) {
            acc += al[2 * k] * w0[k] + al[2 * k + 1] * w1[k];
        }
        s_loc[t * F_ + f] = acc;
    }
    __syncthreads();

    // --- base[t][a] = pq + bq + bm + bl + loc @ Wl ---
    for (int i = tid; i < TT * AD_; i += 256) {
        int a = i & (AD_ - 1);
        int t = i >> 7;
        float acc = pq[b * AD_ + a] + bq[a] + bm[a] + bl[a];
        const float* lrow = &s_loc[t * F_];
#pragma unroll
        for (int f = 0; f < F_; f++) acc += lrow[f] * Wl[f * AD_ + a];
        s_base[i] = acc;
    }
    __syncthreads();

    // --- GEMM: pm[t][a] over MD, register tile 8t x 4a per thread ---
    const int ta = tid & 31;   // a-group: a = ta*4 .. ta*4+3
    const int tt = tid >> 5;   // t-group: t = tt*8 .. tt*8+7
    float acc[8][4];
#pragma unroll
    for (int j = 0; j < 8; j++)
#pragma unroll
        for (int i = 0; i < 4; i++) acc[j][i] = 0.f;

    for (int mc = 0; mc < MD_; mc += MC) {
        // stage memory tile transposed: s_mem[m][t]
        for (int i = tid; i < TT * MC; i += 256) {
            int m = i & (MC - 1);
            int t = i >> 5;
            s_mem[m * 68 + t] = memory[((long)b * T_ + t0 + t) * MD_ + mc + m];
        }
        // stage Wm tile: s_wm[m][a]
        for (int i = tid; i < MC * AD_; i += 256) {
            s_wm[i] = Wm[(mc + (i >> 7)) * AD_ + (i & (AD_ - 1))];
        }
        __syncthreads();

#pragma unroll 4
        for (int m = 0; m < MC; m++) {
            float4 w = *(const float4*)&s_wm[m * AD_ + ta * 4];
            float4 x0 = *(const float4*)&s_mem[m * 68 + tt * 8];
            float4 x1 = *(const float4*)&s_mem[m * 68 + tt * 8 + 4];
            float xv[8] = {x0.x, x0.y, x0.z, x0.w, x1.x, x1.y, x1.z, x1.w};
            float wv[4] = {w.x, w.y, w.z, w.w};
#pragma unroll
            for (int j = 0; j < 8; j++)
#pragma unroll
                for (int i = 0; i < 4; i++) acc[j][i] += xv[j] * wv[i];
        }
        __syncthreads();
    }

    // --- epilogue: tanh, dot with v, reduce over a ---
    float vws[4];
#pragma unroll
    for (int i = 0; i < 4; i++) vws[i] = vw[ta * 4 + i];

#pragma unroll
    for (int j = 0; j < 8; j++) {
        int t = tt * 8 + j;
        float4 bs = *(const float4*)&s_base[t * AD_ + ta * 4];
        float bsv[4] = {bs.x, bs.y, bs.z, bs.w};
        float s = 0.f;
#pragma unroll
        for (int i = 0; i < 4; i++) {
            s += tanhf(acc[j][i] + bsv[i]) * vws[i];
        }
        // reduce across 32 a-threads (xor masks <=16 stay within the 32-group)
        s += __shfl_xor(s, 16);
        s += __shfl_xor(s, 8);
        s += __shfl_xor(s, 4);
        s += __shfl_xor(s, 2);
        s += __shfl_xor(s, 1);
        if (ta == 0) {
            int tg = t0 + t;
            float val = s + vb[0];
            if (mask[(long)b * T_ + tg]) val = -INFINITY;
            scores[b * T_ + tg] = val;
        }
    }
}

// ---------------- K3a: softmax over T per batch ----------------
__global__ __launch_bounds__(256) void k_softmax(const float* __restrict__ scores,
                                                 float* __restrict__ oalign) {
    int b = blockIdx.x;
    int tid = threadIdx.x;
    __shared__ float red[4];
    __shared__ float s_max, s_sum;

    float m = -INFINITY;
    for (int t = tid; t < T_; t += 256) m = fmaxf(m, scores[b * T_ + t]);
    for (int off = 32; off >= 1; off >>= 1) m = fmaxf(m, __shfl_xor(m, off));
    if ((tid & 63) == 0) red[tid >> 6] = m;
    __syncthreads();
    if (tid == 0) {
        float mm = red[0];
        for (int i = 1; i < 4; i++) mm = fmaxf(mm, red[i]);
        s_max = mm;
    }
    __syncthreads();
    float mm = s_max;

    float sum = 0.f;
    for (int t = tid; t < T_; t += 256) sum += expf(scores[b * T_ + t] - mm);
    for (int off = 32; off >= 1; off >>= 1) sum += __shfl_xor(sum, off);
    if ((tid & 63) == 0) red[tid >> 6] = sum;
    __syncthreads();
    if (tid == 0) {
        float ss = 0.f;
        for (int i = 0; i < 4; i++) ss += red[i];
        s_sum = ss;
    }
    __syncthreads();
    float inv = 1.f / s_sum;
    for (int t = tid; t < T_; t += 256) {
        oalign[b * T_ + t] = expf(scores[b * T_ + t] - mm) * inv;
    }
}

// ---------------- K3b: context = alignment @ memory ----------------
__global__ __launch_bounds__(256) void k_context(const float* __restrict__ oalign,
                                                 const float* __restrict__ memory,
                                                 float* __restrict__ ctx) {
    // grid: (B, MD/256, T/512), block 256
    int b = blockIdx.x;
    int md = blockIdx.y * 256 + threadIdx.x;
    int tc = blockIdx.z * 512;
    __shared__ float s_a[512];
    for (int i = threadIdx.x; i < 512; i += 256) s_a[i] = oalign[b * T_ + tc + i];
    __syncthreads();
    float acc = 0.f;
    const float* mp = memory + ((long)b * T_ + tc) * MD_ + md;
#pragma unroll 4
    for (int t = 0; t < 512; t++) acc += s_a[t] * mp[(long)t * MD_];
    atomicAdd(&ctx[b * MD_ + md], acc);
}

extern "C" void kernel_launch(void* const* d_in, const int* in_sizes, int n_in,
                              void* d_out, int out_size, void* d_ws, size_t ws_size,
                              hipStream_t stream) {
    const float* query      = (const float*)d_in[0];   // [B,QD]
    const float* memory     = (const float*)d_in[1];   // [B,T,MD]
    const float* alignments = (const float*)d_in[2];   // [B,T,2]
    const unsigned char* mask = (const unsigned char*)d_in[3]; // [B,T] bool (all false)
    const float* Wq    = (const float*)d_in[4];
    const float* bq    = (const float*)d_in[5];
    const float* Wm    = (const float*)d_in[6];
    const float* bm    = (const float*)d_in[7];
    const float* convw = (const float*)d_in[8];
    const float* convb = (const float*)d_in[9];
    const float* Wl    = (const float*)d_in[10];
    const float* bl    = (const float*)d_in[11];
    const float* vw    = (const float*)d_in[12];
    const float* vb    = (const float*)d_in[13];

    float* out = (float*)d_out;
    float* ctx = out;                      // [B,MD] = 16384
    float* oalign = out + B_ * MD_;        // [B,T]  = 131072

    float* ws = (float*)d_ws;
    float* pq = ws;                        // [B,AD] = 4096
    float* scores = ws + B_ * AD_;         // [B,T]  = 131072

    hipMemsetAsync(pq, 0, B_ * AD_ * sizeof(float), stream);
    hipMemsetAsync(ctx, 0, B_ * MD_ * sizeof(float), stream);

    k_pq<<<dim3(B_, QD_ / 128), 128, 0, stream>>>(query, Wq, pq);
    k_score<<<dim3(T_ / TT, B_), 256, 0, stream>>>(
        memory, alignments, mask, Wm, bm, convw, convb, Wl, bl, vw, vb, pq, bq, scores);
    k_softmax<<<B_, 256, 0, stream>>>(scores, oalign);
    k_context<<<dim3(B_, MD_ / 256, T_ / 512), 256, 0, stream>>>(oalign, memory, ctx);
}

// Round 2
// 550.693 us; speedup vs baseline: 1.5581x; 1.5581x over previous
//
#include <hip/hip_runtime.h>
#include <hip/hip_bf16.h>
#include <math.h>

// Problem constants
#define B_ 32
#define T_ 4096
#define QD_ 1024
#define MD_ 512
#define AD_ 128
#define F_ 32
#define K_ 31
#define PAD_ 15

#define TT 64   // timesteps per score block

typedef float f32x16 __attribute__((ext_vector_type(16)));
typedef unsigned int uint4v __attribute__((ext_vector_type(4)));

// round-half-up float->bf16, packed pair in one VGPR via v_perm
__device__ inline unsigned pk_bf2(float lo, float hi) {
    unsigned ul = __float_as_uint(lo) + 0x8000u;
    unsigned uh = __float_as_uint(hi) + 0x8000u;
    return __builtin_amdgcn_perm(uh, ul, 0x07060302u);
}

__device__ inline unsigned short f2bf_rn(float f) {
    unsigned u = __float_as_uint(f);
    u += 0x7fffu + ((u >> 16) & 1u);
    return (unsigned short)(u >> 16);
}

// v_mfma via inline asm (signature-proof). s_nop 1 covers VALU-write -> MFMA-read hazard.
__device__ inline void mfma32(f32x16& c, uint4v a, uint4v b) {
    asm("s_nop 1\n\tv_mfma_f32_32x32x16_bf16 %0, %1, %2, %0"
        : "+v"(c) : "v"(a), "v"(b));
}

// ---------------- K0: transpose Wm -> bf16 WmT[a][k] ----------------
__global__ __launch_bounds__(256) void k_prep(const float* __restrict__ Wm,
                                              unsigned short* __restrict__ wmT) {
    int i = blockIdx.x * 256 + threadIdx.x;   // 65536 total
    int k = i & (MD_ - 1);
    int a = i >> 9;
    wmT[i] = f2bf_rn(Wm[k * AD_ + a]);
}

// ---------------- K1: processed query ----------------
__global__ __launch_bounds__(128) void k_pq(const float* __restrict__ query,
                                            const float* __restrict__ Wq,
                                            float* __restrict__ pq) {
    int b = blockIdx.x;
    int qc = blockIdx.y;
    int a = threadIdx.x;
    const float* qrow = query + b * QD_ + qc * 128;
    const float* wq = Wq + (qc * 128) * AD_ + a;
    float acc = 0.f;
#pragma unroll 4
    for (int i = 0; i < 128; i++) acc += qrow[i] * wq[i * AD_];
    atomicAdd(&pq[b * AD_ + a], acc);
}

// ---------------- K2: fused conv + projections + MFMA tanh-score ----------------
__global__ __launch_bounds__(256) void k_score(
    const float* __restrict__ memory, const float* __restrict__ alignments,
    const unsigned char* __restrict__ mask,
    const unsigned short* __restrict__ wmT, const float* __restrict__ bm,
    const float* __restrict__ convw, const float* __restrict__ convb,
    const float* __restrict__ Wl, const float* __restrict__ bl,
    const float* __restrict__ vw, const float* __restrict__ vb,
    const float* __restrict__ pq, const float* __restrict__ bq,
    float* __restrict__ scores) {
    __shared__ float s_base[TT * AD_];        // 32 KB
    __shared__ float s_convw[F_ * 2 * K_];
    __shared__ float s_align[(TT + K_ - 1) * 2];
    __shared__ float s_loc[TT * F_];
    __shared__ float s_score[TT];

    const int tid = threadIdx.x;
    const int b = blockIdx.y;
    const int t0 = blockIdx.x * TT;

    if (tid < TT) s_score[tid] = 0.f;

    // --- stage conv weights + alignment window ---
    for (int i = tid; i < F_ * 2 * K_; i += 256) s_convw[i] = convw[i];
    for (int i = tid; i < (TT + K_ - 1) * 2; i += 256) {
        int tg = t0 + (i >> 1) - PAD_;
        s_align[i] = (tg >= 0 && tg < T_) ? alignments[((long)b * T_ + tg) * 2 + (i & 1)] : 0.f;
    }
    __syncthreads();

    // --- location conv: loc[t][f] ---
    for (int i = tid; i < TT * F_; i += 256) {
        int f = i & (F_ - 1);
        int t = i >> 5;
        float acc = convb[f];
        const float* w0 = &s_convw[f * (2 * K_)];
        const float* w1 = w0 + K_;
        const float* al = &s_align[t * 2];
#pragma unroll
        for (int k = 0; k < K_; k++) {
            acc += al[2 * k] * w0[k] + al[2 * k + 1] * w1[k];
        }
        s_loc[t * F_ + f] = acc;
    }
    __syncthreads();

    // --- base[t][a] = pq + bq + bm + bl + loc @ Wl ---
    for (int i = tid; i < TT * AD_; i += 256) {
        int a = i & (AD_ - 1);
        int t = i >> 7;
        float acc = pq[b * AD_ + a] + bq[a] + bm[a] + bl[a];
        const float* lrow = &s_loc[t * F_];
#pragma unroll
        for (int f = 0; f < F_; f++) acc += lrow[f] * Wl[f * AD_ + a];
        s_base[i] = acc;
    }
    __syncthreads();

    // --- MFMA GEMM: pm[64t x 128a] over K=512 ---
    // 8 C-tiles (32x32): wave w owns row-tile rt=w>>1, col-tiles ct0=(w&1)*2, ct0+1
    const int lane = tid & 63;
    const int w = tid >> 6;
    const int rt = w >> 1;
    const int ct0 = (w & 1) * 2;
    const int half = lane >> 5;
    const int l31 = lane & 31;

    const float* arow = memory + ((long)(b * T_ + t0 + rt * 32 + l31)) * MD_ + half * 8;
    const unsigned short* wb0 = wmT + (ct0 * 32 + l31) * MD_ + half * 8;
    const unsigned short* wb1 = wb0 + 32 * MD_;

    f32x16 c0, c1;
#pragma unroll
    for (int i = 0; i < 16; i++) { c0[i] = 0.f; c1[i] = 0.f; }

#pragma unroll 4
    for (int k0 = 0; k0 < MD_; k0 += 16) {
        float4 a0 = *(const float4*)(arow + k0);
        float4 a1 = *(const float4*)(arow + k0 + 4);
        uint4v bf0 = *(const uint4v*)(wb0 + k0);
        uint4v bf1 = *(const uint4v*)(wb1 + k0);
        uint4v af;
        af[0] = pk_bf2(a0.x, a0.y);
        af[1] = pk_bf2(a0.z, a0.w);
        af[2] = pk_bf2(a1.x, a1.y);
        af[3] = pk_bf2(a1.z, a1.w);
        mfma32(c0, af, bf0);
        mfma32(c1, af, bf1);
    }
    // drain MFMA->VALU hazard (inline asm bypasses compiler hazard recognizer)
    asm volatile("s_nop 7\n\ts_nop 7\n\ts_nop 7" ::: "memory");

    // --- epilogue: tanh, dot with v, reduce over a ---
    // C/D layout 32x32: col = lane&31, row = (reg&3) + 8*(reg>>2) + 4*(lane>>5)
    float vwa0 = vw[ct0 * 32 + l31];
    float vwa1 = vw[ct0 * 32 + 32 + l31];
#pragma unroll
    for (int i = 0; i < 16; i++) {
        int t = rt * 32 + (i & 3) + 8 * (i >> 2) + 4 * half;
        float v0 = tanhf(c0[i] + s_base[t * AD_ + ct0 * 32 + l31]) * vwa0;
        float v1 = tanhf(c1[i] + s_base[t * AD_ + ct0 * 32 + 32 + l31]) * vwa1;
        float s = v0 + v1;
        s += __shfl_xor(s, 1);
        s += __shfl_xor(s, 2);
        s += __shfl_xor(s, 4);
        s += __shfl_xor(s, 8);
        s += __shfl_xor(s, 16);
        if (l31 == 0) atomicAdd(&s_score[t], s);
    }
    __syncthreads();

    if (tid < TT) {
        int tg = t0 + tid;
        float val = s_score[tid] + vb[0];
        if (mask[(long)b * T_ + tg]) val = -INFINITY;
        scores[b * T_ + tg] = val;
    }
}

// ---------------- K3a: softmax over T per batch ----------------
__global__ __launch_bounds__(256) void k_softmax(const float* __restrict__ scores,
                                                 float* __restrict__ oalign) {
    int b = blockIdx.x;
    int tid = threadIdx.x;
    __shared__ float red[4];
    __shared__ float s_max, s_sum;

    float m = -INFINITY;
    for (int t = tid; t < T_; t += 256) m = fmaxf(m, scores[b * T_ + t]);
    for (int off = 32; off >= 1; off >>= 1) m = fmaxf(m, __shfl_xor(m, off));
    if ((tid & 63) == 0) red[tid >> 6] = m;
    __syncthreads();
    if (tid == 0) {
        float mm = red[0];
        for (int i = 1; i < 4; i++) mm = fmaxf(mm, red[i]);
        s_max = mm;
    }
    __syncthreads();
    float mm = s_max;

    float sum = 0.f;
    for (int t = tid; t < T_; t += 256) sum += expf(scores[b * T_ + t] - mm);
    for (int off = 32; off >= 1; off >>= 1) sum += __shfl_xor(sum, off);
    if ((tid & 63) == 0) red[tid >> 6] = sum;
    __syncthreads();
    if (tid == 0) {
        float ss = 0.f;
        for (int i = 0; i < 4; i++) ss += red[i];
        s_sum = ss;
    }
    __syncthreads();
    float inv = 1.f / s_sum;
    for (int t = tid; t < T_; t += 256) {
        oalign[b * T_ + t] = expf(scores[b * T_ + t] - mm) * inv;
    }
}

// ---------------- K3b: context = alignment @ memory ----------------
__global__ __launch_bounds__(256) void k_context(const float* __restrict__ oalign,
                                                 const float* __restrict__ memory,
                                                 float* __restrict__ ctx) {
    int b = blockIdx.x;
    int md = blockIdx.y * 256 + threadIdx.x;
    int tc = blockIdx.z * 512;
    __shared__ float s_a[512];
    for (int i = threadIdx.x; i < 512; i += 256) s_a[i] = oalign[b * T_ + tc + i];
    __syncthreads();
    float acc = 0.f;
    const float* mp = memory + ((long)b * T_ + tc) * MD_ + md;
#pragma unroll 4
    for (int t = 0; t < 512; t++) acc += s_a[t] * mp[(long)t * MD_];
    atomicAdd(&ctx[b * MD_ + md], acc);
}

extern "C" void kernel_launch(void* const* d_in, const int* in_sizes, int n_in,
                              void* d_out, int out_size, void* d_ws, size_t ws_size,
                              hipStream_t stream) {
    const float* query      = (const float*)d_in[0];
    const float* memory     = (const float*)d_in[1];
    const float* alignments = (const float*)d_in[2];
    const unsigned char* mask = (const unsigned char*)d_in[3];
    const float* Wq    = (const float*)d_in[4];
    const float* bq    = (const float*)d_in[5];
    const float* Wm    = (const float*)d_in[6];
    const float* bm    = (const float*)d_in[7];
    const float* convw = (const float*)d_in[8];
    const float* convb = (const float*)d_in[9];
    const float* Wl    = (const float*)d_in[10];
    const float* bl    = (const float*)d_in[11];
    const float* vw    = (const float*)d_in[12];
    const float* vb    = (const float*)d_in[13];

    float* out = (float*)d_out;
    float* ctx = out;                      // [B,MD]
    float* oalign = out + B_ * MD_;        // [B,T]

    float* ws = (float*)d_ws;
    float* pq = ws;                        // [B,AD] = 4096 floats
    float* scores = ws + B_ * AD_;         // [B,T]  = 131072 floats
    unsigned short* wmT = (unsigned short*)(ws + B_ * AD_ + B_ * T_); // [AD][MD] bf16

    hipMemsetAsync(pq, 0, B_ * AD_ * sizeof(float), stream);
    hipMemsetAsync(ctx, 0, B_ * MD_ * sizeof(float), stream);

    k_prep<<<(AD_ * MD_) / 256, 256, 0, stream>>>(Wm, wmT);
    k_pq<<<dim3(B_, QD_ / 128), 128, 0, stream>>>(query, Wq, pq);
    k_score<<<dim3(T_ / TT, B_), 256, 0, stream>>>(
        memory, alignments, mask, wmT, bm, convw, convb, Wl, bl, vw, vb, pq, bq, scores);
    k_softmax<<<B_, 256, 0, stream>>>(scores, oalign);
    k_context<<<dim3(B_, MD_ / 256, T_ / 512), 256, 0, stream>>>(oalign, memory, ctx);
}

// Round 3
// 485.480 us; speedup vs baseline: 1.7674x; 1.1343x over previous
//
#include <hip/hip_runtime.h>
#include <hip/hip_bf16.h>
#include <math.h>

// Problem constants
#define B_ 32
#define T_ 4096
#define QD_ 1024
#define MD_ 512
#define AD_ 128
#define F_ 32
#define K_ 31
#define PAD_ 15

#define TT 64   // timesteps per score block
#define NBLK (T_ / TT)   // 64 t-blocks per batch

typedef float f32x16 __attribute__((ext_vector_type(16)));
typedef unsigned int uint4v __attribute__((ext_vector_type(4)));

// round-half-up float->bf16 pair packed in one VGPR via v_perm
__device__ inline unsigned pk_bf2(float lo, float hi) {
    unsigned ul = __float_as_uint(lo) + 0x8000u;
    unsigned uh = __float_as_uint(hi) + 0x8000u;
    return __builtin_amdgcn_perm(uh, ul, 0x07060302u);
}

__device__ inline unsigned short f2bf_rn(float f) {
    unsigned u = __float_as_uint(f);
    u += 0x7fffu + ((u >> 16) & 1u);
    return (unsigned short)(u >> 16);
}

__device__ inline float bf2f(unsigned short u) {
    return __uint_as_float(((unsigned)u) << 16);
}

// v_mfma via inline asm. s_nop 1 covers VALU-write -> MFMA-read hazard.
__device__ inline void mfma32(f32x16& c, uint4v a, uint4v b) {
    asm("s_nop 1\n\tv_mfma_f32_32x32x16_bf16 %0, %1, %2, %0"
        : "+v"(c) : "v"(a), "v"(b));
}

// ---------------- K0: swizzle Wm -> bf16 MFMA-fragment order ----------------
// wmT_sw[((kk*4 + ct)*64 + lane)*8 + j] = bf16(Wm[kk*16 + (lane>>5)*8 + j][ct*32 + (lane&31)])
__global__ __launch_bounds__(256) void k_prep(const float* __restrict__ Wm,
                                              unsigned short* __restrict__ wmT_sw) {
    int gid = blockIdx.x * 256 + threadIdx.x;   // 0..8191
    int kk = gid >> 8;
    int ct = (gid >> 6) & 3;
    int lane = gid & 63;
    int k0 = kk * 16 + (lane >> 5) * 8;
    int a = ct * 32 + (lane & 31);
    unsigned short o[8];
#pragma unroll
    for (int j = 0; j < 8; j++) o[j] = f2bf_rn(Wm[(k0 + j) * AD_ + a]);
    uint4v v;
    v[0] = ((unsigned)o[1] << 16) | o[0];
    v[1] = ((unsigned)o[3] << 16) | o[2];
    v[2] = ((unsigned)o[5] << 16) | o[4];
    v[3] = ((unsigned)o[7] << 16) | o[6];
    *(uint4v*)(wmT_sw + (long)gid * 8) = v;
}

// ---------------- K1: processed query ----------------
__global__ __launch_bounds__(128) void k_pq(const float* __restrict__ query,
                                            const float* __restrict__ Wq,
                                            float* __restrict__ pq) {
    int b = blockIdx.x;
    int qc = blockIdx.y;
    int a = threadIdx.x;
    const float* qrow = query + b * QD_ + qc * 128;
    const float* wq = Wq + (qc * 128) * AD_ + a;
    float acc = 0.f;
#pragma unroll 4
    for (int i = 0; i < 128; i++) acc += qrow[i] * wq[i * AD_];
    atomicAdd(&pq[b * AD_ + a], acc);
}

// ---------------- K2: fused conv + base + MFMA scores + partial context ----
__global__ __launch_bounds__(256, 4) void k_score_ctx(
    const float* __restrict__ memory, const float* __restrict__ alignments,
    const unsigned char* __restrict__ mask,
    const unsigned short* __restrict__ wmT_sw, const float* __restrict__ bm,
    const float* __restrict__ convw, const float* __restrict__ convb,
    const float* __restrict__ Wl, const float* __restrict__ bl,
    const float* __restrict__ vw, const float* __restrict__ vb,
    const float* __restrict__ pq, const float* __restrict__ bq,
    float* __restrict__ scores, float* __restrict__ bmax,
    float* __restrict__ bden, float* __restrict__ num) {
    __shared__ __align__(16) unsigned short s_base[TT * AD_];   // 16384 B (bf16)
    __shared__ __align__(16) unsigned char s_u[16896];          // ph1 conv / ph2 A-chunks
    __shared__ float s_score[TT];
    __shared__ float s_w[TT];

    const int tid = threadIdx.x;
    const int b = blockIdx.y;
    const int blk = blockIdx.x;
    const int t0 = blk * TT;

    float* convw_s = (float*)s_u;            // 1984 floats
    float* align_s = convw_s + 1984;         // 192 floats
    float* loc_s   = align_s + 192;          // 2048 floats
    unsigned short* sab = (unsigned short*)s_u;  // ph2: 2 bufs of 64x40 bf16

    if (tid < TT) s_score[tid] = 0.f;

    // --- stage conv weights + alignment window ---
    for (int i = tid; i < F_ * 2 * K_; i += 256) convw_s[i] = convw[i];
    for (int i = tid; i < (TT + K_ - 1) * 2; i += 256) {
        int tg = t0 + (i >> 1) - PAD_;
        align_s[i] = (tg >= 0 && tg < T_) ? alignments[((long)b * T_ + tg) * 2 + (i & 1)] : 0.f;
    }
    __syncthreads();

    // --- location conv ---
    for (int i = tid; i < TT * F_; i += 256) {
        int f = i & (F_ - 1);
        int t = i >> 5;
        float acc = convb[f];
        const float* w0 = &convw_s[f * (2 * K_)];
        const float* w1 = w0 + K_;
        const float* al = &align_s[t * 2];
#pragma unroll
        for (int k = 0; k < K_; k++) acc += al[2 * k] * w0[k] + al[2 * k + 1] * w1[k];
        loc_s[t * F_ + f] = acc;
    }
    __syncthreads();

    // --- base[t][a] -> bf16 LDS ---
    for (int i = tid; i < TT * AD_; i += 256) {
        int a = i & (AD_ - 1);
        int t = i >> 7;
        float acc = pq[b * AD_ + a] + bq[a] + bm[a] + bl[a];
        const float* lrow = &loc_s[t * F_];
#pragma unroll
        for (int f = 0; f < F_; f++) acc += lrow[f] * Wl[f * AD_ + a];
        s_base[i] = f2bf_rn(acc);
    }
    __syncthreads();   // loc_s dead after this; ph2 may reuse s_u

    // --- MFMA GEMM over K=512, A staged via LDS (bf16, row stride 40) ---
    const int lane = tid & 63;
    const int w = tid >> 6;
    const int rt = w >> 1;
    const int ct0 = (w & 1) * 2;
    const int half = lane >> 5;
    const int l31 = lane & 31;

    // staging map: thread -> rows (tid>>3) and (tid>>3)+32, cols (tid&7)*4
    const int srow = tid >> 3;
    const int skq = (tid & 7) * 4;
    const float* aptr = memory + ((long)b * T_ + t0) * MD_;
    const float* g_lo = aptr + srow * MD_ + skq;
    const float* g_hi = aptr + (srow + 32) * MD_ + skq;
    unsigned short* w_lo[2], * w_hi[2];
    w_lo[0] = sab + srow * 40 + skq;          w_hi[0] = sab + (srow + 32) * 40 + skq;
    w_lo[1] = w_lo[0] + 2560;                 w_hi[1] = w_hi[0] + 2560;

    const unsigned short* bptr = wmT_sw + ((long)ct0 * 64 + lane) * 8;
    const int arow = (rt * 32 + l31) * 40 + half * 8;   // ushort idx in chunk buf

    f32x16 c0, c1;
#pragma unroll
    for (int i = 0; i < 16; i++) { c0[i] = 0.f; c1[i] = 0.f; }

    // prologue: chunk 0
    float4 A0 = *(const float4*)(g_lo);
    float4 A1 = *(const float4*)(g_hi);
    uint4v B00 = *(const uint4v*)(bptr);
    uint4v B01 = *(const uint4v*)(bptr + 512);
    uint4v B10 = *(const uint4v*)(bptr + 2048);
    uint4v B11 = *(const uint4v*)(bptr + 2048 + 512);
    ((unsigned*)w_lo[0])[0] = pk_bf2(A0.x, A0.y);
    ((unsigned*)w_lo[0])[1] = pk_bf2(A0.z, A0.w);
    ((unsigned*)w_hi[0])[0] = pk_bf2(A1.x, A1.y);
    ((unsigned*)w_hi[0])[1] = pk_bf2(A1.z, A1.w);
    __syncthreads();

    for (int c = 0; c < 16; c++) {
        const int cb = c & 1, nb = cb ^ 1;
        // prefetch chunk c+1 (A from HBM, B from L2)
        float4 N0, N1;
        uint4v NB00, NB01, NB10, NB11;
        {
            int kcn = (c < 15) ? (c + 1) * 32 : 0;
            N0 = *(const float4*)(g_lo + kcn);
            N1 = *(const float4*)(g_hi + kcn);
            long kkn = (c < 15) ? (long)(2 * c + 2) * 2048 : 0;
            NB00 = *(const uint4v*)(bptr + kkn);
            NB01 = *(const uint4v*)(bptr + kkn + 512);
            NB10 = *(const uint4v*)(bptr + kkn + 2048);
            NB11 = *(const uint4v*)(bptr + kkn + 2048 + 512);
        }
        // compute chunk c
        uint4v af0 = *(const uint4v*)(sab + cb * 2560 + arow);
        uint4v af1 = *(const uint4v*)(sab + cb * 2560 + arow + 16);
        mfma32(c0, af0, B00);
        mfma32(c1, af0, B01);
        mfma32(c0, af1, B10);
        mfma32(c1, af1, B11);
        B00 = NB00; B01 = NB01; B10 = NB10; B11 = NB11;
        // write chunk c+1
        if (c < 15) {
            ((unsigned*)w_lo[nb])[0] = pk_bf2(N0.x, N0.y);
            ((unsigned*)w_lo[nb])[1] = pk_bf2(N0.z, N0.w);
            ((unsigned*)w_hi[nb])[0] = pk_bf2(N1.x, N1.y);
            ((unsigned*)w_hi[nb])[1] = pk_bf2(N1.z, N1.w);
        }
        __syncthreads();
    }
    // drain MFMA->VALU hazard
    asm volatile("s_nop 7\n\ts_nop 7\n\ts_nop 7" ::: "memory");

    // --- epilogue: tanh, dot with v, reduce over a ---
    float vwa0 = vw[ct0 * 32 + l31];
    float vwa1 = vw[ct0 * 32 + 32 + l31];
#pragma unroll
    for (int i = 0; i < 16; i++) {
        int t = rt * 32 + (i & 3) + 8 * (i >> 2) + 4 * half;
        float b0 = bf2f(s_base[t * AD_ + ct0 * 32 + l31]);
        float b1 = bf2f(s_base[t * AD_ + ct0 * 32 + 32 + l31]);
        float s = tanhf(c0[i] + b0) * vwa0 + tanhf(c1[i] + b1) * vwa1;
        s += __shfl_xor(s, 1);
        s += __shfl_xor(s, 2);
        s += __shfl_xor(s, 4);
        s += __shfl_xor(s, 8);
        s += __shfl_xor(s, 16);
        if (l31 == 0) atomicAdd(&s_score[t], s);
    }
    __syncthreads();

    // --- local softmax stats (one wave) ---
    if (tid < TT) {
        float s = s_score[tid] + vb[0];
        bool mk = mask[(long)b * T_ + t0 + tid] != 0;
        if (mk) s = -INFINITY;
        scores[b * T_ + t0 + tid] = s;
        float m = s;
#pragma unroll
        for (int off = 32; off >= 1; off >>= 1) m = fmaxf(m, __shfl_xor(m, off));
        float e = (m == -INFINITY) ? 0.f : expf(s - m);
        float d = e;
#pragma unroll
        for (int off = 32; off >= 1; off >>= 1) d += __shfl_xor(d, off);
        s_w[tid] = e;
        if (tid == 0) {
            bmax[b * NBLK + blk] = m;
            bden[b * NBLK + blk] = d;
        }
    }
    __syncthreads();

    // --- partial context: num[md] = sum_t e^{s_t - m} * mem[t][md] (tile re-read, L2/LLC-hot) ---
    {
        const float2* mp = (const float2*)aptr + tid;   // md pair = 2*tid
        float ax = 0.f, ay = 0.f;
#pragma unroll 8
        for (int t = 0; t < TT; t++) {
            float2 v = mp[t * 256];
            float wt = s_w[t];
            ax += wt * v.x;
            ay += wt * v.y;
        }
        float2 o; o.x = ax; o.y = ay;
        *(float2*)(num + ((long)b * NBLK + blk) * MD_ + tid * 2) = o;
    }
}

// ---------------- K3: combine partials -> ctx + oalign ----------------
__global__ __launch_bounds__(512) void k_reduce(
    const float* __restrict__ bmax, const float* __restrict__ bden,
    const float* __restrict__ num, const float* __restrict__ scores,
    float* __restrict__ ctx, float* __restrict__ oalign) {
    int b = blockIdx.x;
    int tid = threadIdx.x;
    __shared__ float sm[NBLK], se[NBLK];
    __shared__ float sD;
    if (tid < NBLK) sm[tid] = bmax[b * NBLK + tid];
    __syncthreads();
    float M = -INFINITY;
#pragma unroll
    for (int i = 0; i < NBLK; i++) M = fmaxf(M, sm[i]);
    if (tid < NBLK) se[tid] = expf(sm[tid] - M) * bden[b * NBLK + tid];
    __syncthreads();
    if (tid == 0) {
        float D = 0.f;
        for (int i = 0; i < NBLK; i++) D += se[i];
        sD = D;
    }
    if (tid < NBLK) se[tid] = expf(sm[tid] - M);   // scale factors
    __syncthreads();
    float invD = 1.f / sD;

    // ctx
    float acc = 0.f;
    const float* np = num + (long)b * NBLK * MD_ + tid;
#pragma unroll 8
    for (int blk = 0; blk < NBLK; blk++) acc += se[blk] * np[blk * MD_];
    ctx[b * MD_ + tid] = acc * invD;

    // alignments
    for (int t = tid; t < T_; t += 512) {
        oalign[b * T_ + t] = expf(scores[b * T_ + t] - M) * invD;
    }
}

extern "C" void kernel_launch(void* const* d_in, const int* in_sizes, int n_in,
                              void* d_out, int out_size, void* d_ws, size_t ws_size,
                              hipStream_t stream) {
    const float* query      = (const float*)d_in[0];
    const float* memory     = (const float*)d_in[1];
    const float* alignments = (const float*)d_in[2];
    const unsigned char* mask = (const unsigned char*)d_in[3];
    const float* Wq    = (const float*)d_in[4];
    const float* bq    = (const float*)d_in[5];
    const float* Wm    = (const float*)d_in[6];
    const float* bm    = (const float*)d_in[7];
    const float* convw = (const float*)d_in[8];
    const float* convb = (const float*)d_in[9];
    const float* Wl    = (const float*)d_in[10];
    const float* bl    = (const float*)d_in[11];
    const float* vw    = (const float*)d_in[12];
    const float* vb    = (const float*)d_in[13];

    float* out = (float*)d_out;
    float* ctx = out;                      // [B,MD]
    float* oalign = out + B_ * MD_;        // [B,T]

    float* ws = (float*)d_ws;
    float* pq     = ws;                               // 4096 floats
    float* scores = pq + B_ * AD_;                    // 131072 floats
    float* bmax   = scores + B_ * T_;                 // 2048
    float* bden   = bmax + B_ * NBLK;                 // 2048
    float* num    = bden + B_ * NBLK;                 // 32*64*512 = 1048576 floats
    unsigned short* wmT_sw = (unsigned short*)(num + (long)B_ * NBLK * MD_); // 65536*8 B... 524288 ushorts? no: 8192*8=65536 entries

    hipMemsetAsync(pq, 0, B_ * AD_ * sizeof(float), stream);

    k_prep<<<32, 256, 0, stream>>>(Wm, wmT_sw);
    k_pq<<<dim3(B_, QD_ / 128), 128, 0, stream>>>(query, Wq, pq);
    k_score_ctx<<<dim3(NBLK, B_), 256, 0, stream>>>(
        memory, alignments, mask, wmT_sw, bm, convw, convb, Wl, bl, vw, vb, pq, bq,
        scores, bmax, bden, num);
    k_reduce<<<B_, 512, 0, stream>>>(bmax, bden, num, scores, ctx, oalign);
}